// Round 5
// baseline (97.087 us; speedup 1.0000x reference)
//
#include <hip/hip_runtime.h>
#include <math.h>

#define NN 3072
#define FEAT 512
#define HD 64           // 8 heads x 8 dims
#define NE 100000
#define ALPHA 0.2f
#define CAP 96          // max neighbors per row (mean ~7)
#define CAPP 97         // padded for LDS bank spread
#define K5_BLOCKS 2048

// K1 (fused): even blocks do Wh GEMM (raw-W reads, split-K over 4 waves);
//             odd blocks do adj->neighbor-list compaction (wave per row).
// Also zeroes the K3 completion counter (block 0).
__global__ __launch_bounds__(256) void k_stage1(const float* __restrict__ adj, const float* __restrict__ x,
                                                const float* __restrict__ W, const float* __restrict__ a1,
                                                const float* __restrict__ a2, int* __restrict__ nbr,
                                                int* __restrict__ cnt, float* __restrict__ Wh,
                                                float* __restrict__ s1t, float* __restrict__ s2t,
                                                unsigned* __restrict__ counter) {
    __shared__ float xs[4][FEAT];
    __shared__ float part[4][4][HD];
    int b = blockIdx.x;
    int tid = threadIdx.x;
    if (b == 0 && tid == 0) counter[0] = 0;   // reset for K3's last-block detection (every call)
    int wid = tid >> 6, lane = tid & 63;

    if (b & 1) {
        // ---- pre role: rows (b>>1)*4 + wid ----
        int i = (b >> 1) * 4 + wid;
        const float4* row = (const float4*)&adj[(size_t)i * NN];
        float4 v[12];
        #pragma unroll
        for (int c = 0; c < 12; ++c) v[c] = row[c * 64 + lane];   // all 12 loads in flight
        unsigned long long lmask = (1ull << lane) - 1ull;
        int base = 0;
        #pragma unroll
        for (int c = 0; c < 12; ++c) {
            #pragma unroll
            for (int k = 0; k < 4; ++k) {
                float vk = k == 0 ? v[c].x : k == 1 ? v[c].y : k == 2 ? v[c].z : v[c].w;
                bool nz = vk > 0.f;
                unsigned long long m = __ballot(nz);
                if (nz) {
                    int pos = base + __popcll(m & lmask);
                    if (pos < CAP) nbr[i * CAP + pos] = c * 256 + lane * 4 + k;
                }
                base += __popcll(m);
            }
        }
        if (lane == 0) cnt[i] = base < CAP ? base : CAP;
    } else {
        // ---- wh role: rows n0..n0+3, K split over 4 waves ----
        int n0 = (b >> 1) * 4;
        for (int idx = tid; idx < 512; idx += 256) {          // stage 4 rows of x as float4
            int r = idx >> 7, fq = idx & 127;
            *(float4*)&xs[r][fq * 4] = ((const float4*)x)[(size_t)(n0 + r) * (FEAT / 4) + fq];
        }
        __syncthreads();
        const float* wp = W + (lane >> 3) * (FEAT * 8) + (lane & 7);  // column base for this lane
        int f0 = wid * (FEAT / 4);
        float acc0 = 0.f, acc1 = 0.f, acc2 = 0.f, acc3 = 0.f;
        #pragma unroll 8
        for (int f = f0; f < f0 + FEAT / 4; ++f) {
            float wt = wp[f * 8];
            acc0 = fmaf(xs[0][f], wt, acc0);
            acc1 = fmaf(xs[1][f], wt, acc1);
            acc2 = fmaf(xs[2][f], wt, acc2);
            acc3 = fmaf(xs[3][f], wt, acc3);
        }
        part[wid][0][lane] = acc0;
        part[wid][1][lane] = acc1;
        part[wid][2][lane] = acc2;
        part[wid][3][lane] = acc3;
        __syncthreads();
        int n = n0 + wid;                                     // wave w finalizes row n0+w
        float v = part[0][wid][lane] + part[1][wid][lane] + part[2][wid][lane] + part[3][wid][lane];
        Wh[n * HD + lane] = v;
        float t1 = v * a1[lane];
        float t2 = v * a2[lane];
        for (int m = 1; m < 8; m <<= 1) {
            t1 += __shfl_xor(t1, m, 64);
            t2 += __shfl_xor(t2, m, 64);
        }
        if ((lane & 7) == 0) {
            int h = lane >> 3;
            s1t[n * 8 + h] = t1;
            s2t[n * 8 + h] = t2;
        }
    }
}

// K2: attention + ELU + fused P/Q. Wave per row; lane = h*8+d.
__global__ __launch_bounds__(256) void k_attn_pq(const float* __restrict__ Wh, const float* __restrict__ s1t,
                                                 const float* __restrict__ s2t, const int* __restrict__ nbr,
                                                 const int* __restrict__ cnt, const float* __restrict__ W1,
                                                 const float* __restrict__ b1, float* __restrict__ P,
                                                 float* __restrict__ Q) {
    __shared__ int   jbuf[4][CAP];
    __shared__ float ebuf[4][8][CAPP];
    __shared__ float es[4][HD];
    int wid = threadIdx.x >> 6;
    int lane = threadIdx.x & 63;
    int i = blockIdx.x * 4 + wid;
    int h = lane >> 3, d = lane & 7;
    int ni = cnt[i];
    for (int k = lane; k < CAP; k += 64)
        if (k < ni) jbuf[wid][k] = nbr[i * CAP + k];
    __syncthreads();
    float s1i = s1t[i * 8 + h];
    float mloc = -INFINITY;
    for (int k = d; k < ni; k += 8) {
        int j = jbuf[wid][k];
        float ev = s1i + s2t[j * 8 + h];
        ev = ev > 0.f ? ev : ALPHA * ev;
        ebuf[wid][h][k] = ev;
        mloc = fmaxf(mloc, ev);
    }
    mloc = fmaxf(mloc, __shfl_xor(mloc, 1, 8));
    mloc = fmaxf(mloc, __shfl_xor(mloc, 2, 8));
    mloc = fmaxf(mloc, __shfl_xor(mloc, 4, 8));
    __syncthreads();
    float denom = 0.f, acc = 0.f;
    for (int k = 0; k < ni; ++k) {
        float p = __expf(ebuf[wid][h][k] - mloc);
        denom += p;
        acc = fmaf(p, Wh[jbuf[wid][k] * HD + lane], acc);
    }
    float o = acc / denom;
    o = o > 0.f ? o : expm1f(o);                  // ELU
    es[wid][lane] = o;
    __syncthreads();
    float p = b1[lane], q = 0.f;
    #pragma unroll 8
    for (int k = 0; k < HD; ++k) {
        float e = es[wid][k];
        p = fmaf(e, W1[k * HD + lane], p);
        q = fmaf(e, W1[(HD + k) * HD + lane], q);
    }
    P[i * HD + lane] = p;
    Q[i * HD + lane] = q;
}

// K3: edge classifier + NLL + fused deterministic final reduce (last block sums
// all partials in fixed order; identity of last block is timing-dependent but
// the summation order is not).
__global__ __launch_bounds__(256) void k_cls(const float* __restrict__ P, const float* __restrict__ Q,
                                             const int* __restrict__ L, const int* __restrict__ R,
                                             const int* __restrict__ label, const float* __restrict__ W2,
                                             const float* __restrict__ b2, float* __restrict__ partials,
                                             unsigned* __restrict__ counter, float* __restrict__ out) {
    int tid = threadIdx.x;
    int sl = tid & 15;
    int grp = (blockIdx.x * 256 + tid) >> 4;
    int ngrp = gridDim.x * 16;
    float2 wa = *(const float2*)&W2[(sl * 4 + 0) * 2];
    float2 wb = *(const float2*)&W2[(sl * 4 + 1) * 2];
    float2 wc = *(const float2*)&W2[(sl * 4 + 2) * 2];
    float2 wd = *(const float2*)&W2[(sl * 4 + 3) * 2];
    float b20 = b2[0], b21 = b2[1];
    float sum = 0.f;
    for (int e = grp; e < NE; e += ngrp) {
        int ln = L[e], rn = R[e];
        float4 p = *(const float4*)&P[ln * HD + sl * 4];
        float4 q = *(const float4*)&Q[rn * HD + sl * 4];
        float v0 = fmaxf(p.x + q.x, 0.f);
        float v1 = fmaxf(p.y + q.y, 0.f);
        float v2 = fmaxf(p.z + q.z, 0.f);
        float v3 = fmaxf(p.w + q.w, 0.f);
        float t0 = v0 * wa.x + v1 * wb.x + v2 * wc.x + v3 * wd.x;
        float t1 = v0 * wa.y + v1 * wb.y + v2 * wc.y + v3 * wd.y;
        #pragma unroll
        for (int m = 1; m < 16; m <<= 1) {
            t0 += __shfl_xor(t0, m, 64);
            t1 += __shfl_xor(t1, m, 64);
        }
        if (sl == 0) {
            float l0 = t0 + b20, l1 = t1 + b21;
            float mx = fmaxf(l0, l1);
            float lse = mx + __logf(__expf(l0 - mx) + __expf(l1 - mx));
            float sel = label[e] ? l1 : l0;
            sum += lse - sel;
        }
    }
    __shared__ float red[256];
    __shared__ int lastflag;
    red[tid] = sum;
    __syncthreads();
    for (int s = 128; s > 0; s >>= 1) {
        if (tid < s) red[tid] += red[tid + s];
        __syncthreads();
    }
    if (tid == 0) {
        __hip_atomic_store(&partials[blockIdx.x], red[0], __ATOMIC_RELEASE, __HIP_MEMORY_SCOPE_AGENT);
        unsigned old = __hip_atomic_fetch_add(counter, 1u, __ATOMIC_ACQ_REL, __HIP_MEMORY_SCOPE_AGENT);
        lastflag = (old == (unsigned)(gridDim.x - 1));
    }
    __syncthreads();
    if (lastflag) {
        float s = 0.f;
        for (int k = tid; k < K5_BLOCKS; k += 256)   // fixed strided order: deterministic
            s += __hip_atomic_load(&partials[k], __ATOMIC_ACQUIRE, __HIP_MEMORY_SCOPE_AGENT);
        __syncthreads();
        red[tid] = s;
        __syncthreads();
        for (int s2 = 128; s2 > 0; s2 >>= 1) {
            if (tid < s2) red[tid] += red[tid + s2];
            __syncthreads();
        }
        if (tid == 0) out[0] = red[0] / (float)NE;
    }
}

extern "C" void kernel_launch(void* const* d_in, const int* in_sizes, int n_in,
                              void* d_out, int out_size, void* d_ws, size_t ws_size,
                              hipStream_t stream) {
    const float* x     = (const float*)d_in[0];
    const float* adj   = (const float*)d_in[1];
    const int*   L     = (const int*)d_in[2];
    const int*   R     = (const int*)d_in[3];
    const int*   label = (const int*)d_in[4];
    const float* W     = (const float*)d_in[5];
    const float* a1    = (const float*)d_in[6];
    const float* a2    = (const float*)d_in[7];
    const float* W1    = (const float*)d_in[8];
    const float* b1    = (const float*)d_in[9];
    const float* W2    = (const float*)d_in[10];
    const float* b2    = (const float*)d_in[11];

    char* ws = (char*)d_ws;
    float*    Wh       = (float*)   (ws + 0);         //  786432 B
    float*    s1t      = (float*)   (ws + 786432);    //   98304 B   [N][8]
    float*    s2t      = (float*)   (ws + 884736);    //   98304 B   [N][8]
    int*      cnt      = (int*)     (ws + 983040);    //   12288 B
    int*      nbr      = (int*)     (ws + 995328);    // 1179648 B
    float*    P        = (float*)   (ws + 2174976);   //  786432 B
    float*    Q        = (float*)   (ws + 2961408);   //  786432 B
    float*    partials = (float*)   (ws + 3747840);   //    8192 B
    unsigned* counter  = (unsigned*)(ws + 3756032);   //       4 B

    k_stage1<<<2 * (NN / 4), 256, 0, stream>>>(adj, x, W, a1, a2, nbr, cnt, Wh, s1t, s2t, counter);
    k_attn_pq<<<NN / 4, 256, 0, stream>>>(Wh, s1t, s2t, nbr, cnt, W1, b1, P, Q);
    k_cls<<<K5_BLOCKS, 256, 0, stream>>>(P, Q, L, R, label, W2, b2, partials, counter, (float*)d_out);
}

// Round 6
// 37.792 us; speedup vs baseline: 2.5690x; 2.5690x over previous
//
#include <hip/hip_runtime.h>
#include <math.h>

#define NN 3072
#define FEAT 512
#define HD 64           // 8 heads x 8 dims
#define NE 100000
#define ALPHA 0.2f
#define CAP 96          // max neighbors per row (mean ~7)
#define CAPP 97         // padded for LDS bank spread
#define K5_BLOCKS 2048

// K1 (fused): even blocks do Wh GEMM (raw-W reads, split-K over 4 waves);
//             odd blocks do adj->neighbor-list compaction (wave per row).
__global__ __launch_bounds__(256) void k_stage1(const float* __restrict__ adj, const float* __restrict__ x,
                                                const float* __restrict__ W, const float* __restrict__ a1,
                                                const float* __restrict__ a2, int* __restrict__ nbr,
                                                int* __restrict__ cnt, float* __restrict__ Wh,
                                                float* __restrict__ s1t, float* __restrict__ s2t) {
    __shared__ float xs[4][FEAT];
    __shared__ float part[4][4][HD];
    int b = blockIdx.x;
    int tid = threadIdx.x;
    int wid = tid >> 6, lane = tid & 63;

    if (b & 1) {
        // ---- pre role: rows (b>>1)*4 + wid ----
        int i = (b >> 1) * 4 + wid;
        const float4* row = (const float4*)&adj[(size_t)i * NN];
        float4 v[12];
        #pragma unroll
        for (int c = 0; c < 12; ++c) v[c] = row[c * 64 + lane];   // all 12 loads in flight
        unsigned long long lmask = (1ull << lane) - 1ull;
        int base = 0;
        #pragma unroll
        for (int c = 0; c < 12; ++c) {
            #pragma unroll
            for (int k = 0; k < 4; ++k) {
                float vk = k == 0 ? v[c].x : k == 1 ? v[c].y : k == 2 ? v[c].z : v[c].w;
                bool nz = vk > 0.f;
                unsigned long long m = __ballot(nz);
                if (nz) {
                    int pos = base + __popcll(m & lmask);
                    if (pos < CAP) nbr[i * CAP + pos] = c * 256 + lane * 4 + k;
                }
                base += __popcll(m);
            }
        }
        if (lane == 0) cnt[i] = base < CAP ? base : CAP;
    } else {
        // ---- wh role: rows n0..n0+3, K split over 4 waves ----
        int n0 = (b >> 1) * 4;
        for (int idx = tid; idx < 512; idx += 256) {          // stage 4 rows of x as float4
            int r = idx >> 7, fq = idx & 127;
            *(float4*)&xs[r][fq * 4] = ((const float4*)x)[(size_t)(n0 + r) * (FEAT / 4) + fq];
        }
        __syncthreads();
        const float* wp = W + (lane >> 3) * (FEAT * 8) + (lane & 7);  // column base for this lane
        int f0 = wid * (FEAT / 4);
        float acc0 = 0.f, acc1 = 0.f, acc2 = 0.f, acc3 = 0.f;
        #pragma unroll 8
        for (int f = f0; f < f0 + FEAT / 4; ++f) {
            float wt = wp[f * 8];
            acc0 = fmaf(xs[0][f], wt, acc0);
            acc1 = fmaf(xs[1][f], wt, acc1);
            acc2 = fmaf(xs[2][f], wt, acc2);
            acc3 = fmaf(xs[3][f], wt, acc3);
        }
        part[wid][0][lane] = acc0;
        part[wid][1][lane] = acc1;
        part[wid][2][lane] = acc2;
        part[wid][3][lane] = acc3;
        __syncthreads();
        int n = n0 + wid;                                     // wave w finalizes row n0+w
        float v = part[0][wid][lane] + part[1][wid][lane] + part[2][wid][lane] + part[3][wid][lane];
        Wh[n * HD + lane] = v;
        float t1 = v * a1[lane];
        float t2 = v * a2[lane];
        for (int m = 1; m < 8; m <<= 1) {
            t1 += __shfl_xor(t1, m, 64);
            t2 += __shfl_xor(t2, m, 64);
        }
        if ((lane & 7) == 0) {
            int h = lane >> 3;
            s1t[n * 8 + h] = t1;
            s2t[n * 8 + h] = t2;
        }
    }
}

// K2: attention + ELU + fused P/Q. Wave per row; lane = h*8+d.
__global__ __launch_bounds__(256) void k_attn_pq(const float* __restrict__ Wh, const float* __restrict__ s1t,
                                                 const float* __restrict__ s2t, const int* __restrict__ nbr,
                                                 const int* __restrict__ cnt, const float* __restrict__ W1,
                                                 const float* __restrict__ b1, float* __restrict__ P,
                                                 float* __restrict__ Q) {
    __shared__ int   jbuf[4][CAP];
    __shared__ float ebuf[4][8][CAPP];
    __shared__ float es[4][HD];
    int wid = threadIdx.x >> 6;
    int lane = threadIdx.x & 63;
    int i = blockIdx.x * 4 + wid;
    int h = lane >> 3, d = lane & 7;
    int ni = cnt[i];
    for (int k = lane; k < CAP; k += 64)
        if (k < ni) jbuf[wid][k] = nbr[i * CAP + k];
    __syncthreads();
    float s1i = s1t[i * 8 + h];
    float mloc = -INFINITY;
    for (int k = d; k < ni; k += 8) {
        int j = jbuf[wid][k];
        float ev = s1i + s2t[j * 8 + h];
        ev = ev > 0.f ? ev : ALPHA * ev;
        ebuf[wid][h][k] = ev;
        mloc = fmaxf(mloc, ev);
    }
    mloc = fmaxf(mloc, __shfl_xor(mloc, 1, 8));
    mloc = fmaxf(mloc, __shfl_xor(mloc, 2, 8));
    mloc = fmaxf(mloc, __shfl_xor(mloc, 4, 8));
    __syncthreads();
    float denom = 0.f, acc = 0.f;
    for (int k = 0; k < ni; ++k) {
        float p = __expf(ebuf[wid][h][k] - mloc);
        denom += p;
        acc = fmaf(p, Wh[jbuf[wid][k] * HD + lane], acc);
    }
    float o = acc / denom;
    o = o > 0.f ? o : expm1f(o);                  // ELU
    es[wid][lane] = o;
    __syncthreads();
    float p = b1[lane], q = 0.f;
    #pragma unroll 8
    for (int k = 0; k < HD; ++k) {
        float e = es[wid][k];
        p = fmaf(e, W1[k * HD + lane], p);
        q = fmaf(e, W1[(HD + k) * HD + lane], q);
    }
    P[i * HD + lane] = p;
    Q[i * HD + lane] = q;
}

// K3: 16 lanes per edge, float4 loads. h1 = relu(P[L]+Q[R]); logits = h1@W2+b2; nll.
//     Plain per-block partial store (NO atomics — round-5 showed agent-scope
//     release/acquire per block costs ~70 us in cache-maintenance serialization).
__global__ __launch_bounds__(256) void k_cls(const float* __restrict__ P, const float* __restrict__ Q,
                                             const int* __restrict__ L, const int* __restrict__ R,
                                             const int* __restrict__ label, const float* __restrict__ W2,
                                             const float* __restrict__ b2, float* __restrict__ partials) {
    int tid = threadIdx.x;
    int sl = tid & 15;
    int grp = (blockIdx.x * 256 + tid) >> 4;
    int ngrp = gridDim.x * 16;
    float2 wa = *(const float2*)&W2[(sl * 4 + 0) * 2];
    float2 wb = *(const float2*)&W2[(sl * 4 + 1) * 2];
    float2 wc = *(const float2*)&W2[(sl * 4 + 2) * 2];
    float2 wd = *(const float2*)&W2[(sl * 4 + 3) * 2];
    float b20 = b2[0], b21 = b2[1];
    float sum = 0.f;
    for (int e = grp; e < NE; e += ngrp) {
        int ln = L[e], rn = R[e];
        float4 p = *(const float4*)&P[ln * HD + sl * 4];
        float4 q = *(const float4*)&Q[rn * HD + sl * 4];
        float v0 = fmaxf(p.x + q.x, 0.f);
        float v1 = fmaxf(p.y + q.y, 0.f);
        float v2 = fmaxf(p.z + q.z, 0.f);
        float v3 = fmaxf(p.w + q.w, 0.f);
        float t0 = v0 * wa.x + v1 * wb.x + v2 * wc.x + v3 * wd.x;
        float t1 = v0 * wa.y + v1 * wb.y + v2 * wc.y + v3 * wd.y;
        #pragma unroll
        for (int m = 1; m < 16; m <<= 1) {
            t0 += __shfl_xor(t0, m, 64);
            t1 += __shfl_xor(t1, m, 64);
        }
        if (sl == 0) {
            float l0 = t0 + b20, l1 = t1 + b21;
            float mx = fmaxf(l0, l1);
            float lse = mx + __logf(__expf(l0 - mx) + __expf(l1 - mx));
            float sel = label[e] ? l1 : l0;
            sum += lse - sel;
        }
    }
    __shared__ float red[256];
    red[tid] = sum;
    __syncthreads();
    for (int s = 128; s > 0; s >>= 1) {
        if (tid < s) red[tid] += red[tid + s];
        __syncthreads();
    }
    if (tid == 0) partials[blockIdx.x] = red[0];
}

// K4: reduce 2048 partials -> mean
__global__ __launch_bounds__(1024) void k_reduce(const float* __restrict__ partials, float* __restrict__ out) {
    __shared__ float sh[1024];
    int t = threadIdx.x;
    sh[t] = partials[t] + partials[t + 1024];
    __syncthreads();
    for (int s = 512; s > 0; s >>= 1) {
        if (t < s) sh[t] += sh[t + s];
        __syncthreads();
    }
    if (t == 0) out[0] = sh[0] / (float)NE;
}

extern "C" void kernel_launch(void* const* d_in, const int* in_sizes, int n_in,
                              void* d_out, int out_size, void* d_ws, size_t ws_size,
                              hipStream_t stream) {
    const float* x     = (const float*)d_in[0];
    const float* adj   = (const float*)d_in[1];
    const int*   L     = (const int*)d_in[2];
    const int*   R     = (const int*)d_in[3];
    const int*   label = (const int*)d_in[4];
    const float* W     = (const float*)d_in[5];
    const float* a1    = (const float*)d_in[6];
    const float* a2    = (const float*)d_in[7];
    const float* W1    = (const float*)d_in[8];
    const float* b1    = (const float*)d_in[9];
    const float* W2    = (const float*)d_in[10];
    const float* b2    = (const float*)d_in[11];

    char* ws = (char*)d_ws;
    float* Wh       = (float*)(ws + 0);         //  786432 B
    float* s1t      = (float*)(ws + 786432);    //   98304 B   [N][8]
    float* s2t      = (float*)(ws + 884736);    //   98304 B   [N][8]
    int*   cnt      = (int*)  (ws + 983040);    //   12288 B
    int*   nbr      = (int*)  (ws + 995328);    // 1179648 B
    float* P        = (float*)(ws + 2174976);   //  786432 B
    float* Q        = (float*)(ws + 2961408);   //  786432 B
    float* partials = (float*)(ws + 3747840);   //    8192 B

    k_stage1<<<2 * (NN / 4), 256, 0, stream>>>(adj, x, W, a1, a2, nbr, cnt, Wh, s1t, s2t);
    k_attn_pq<<<NN / 4, 256, 0, stream>>>(Wh, s1t, s2t, nbr, cnt, W1, b1, P, Q);
    k_cls<<<K5_BLOCKS, 256, 0, stream>>>(P, Q, L, R, label, W2, b2, partials);
    k_reduce<<<1, 1024, 0, stream>>>(partials, (float*)d_out);
}

// Round 7
// 37.240 us; speedup vs baseline: 2.6071x; 1.0148x over previous
//
#include <hip/hip_runtime.h>
#include <math.h>

#define NN 3072
#define FEAT 512
#define HD 64           // 8 heads x 8 dims
#define NE 100000
#define ALPHA 0.2f
#define CAP 96          // max neighbors per row (mean ~7)
#define CAPP 97         // padded for LDS bank spread
#define AROWS 8         // rows per attn block (8 waves)
#define K5_BLOCKS 2048

// K1 (fused): even blocks do Wh GEMM (raw-W reads, split-K over 4 waves);
//             odd blocks do adj->neighbor-list compaction (wave per row).
__global__ __launch_bounds__(256) void k_stage1(const float* __restrict__ adj, const float* __restrict__ x,
                                                const float* __restrict__ W, const float* __restrict__ a1,
                                                const float* __restrict__ a2, int* __restrict__ nbr,
                                                int* __restrict__ cnt, float* __restrict__ Wh,
                                                float* __restrict__ s1t, float* __restrict__ s2t) {
    __shared__ float xs[4][FEAT];
    __shared__ float part[4][4][HD];
    int b = blockIdx.x;
    int tid = threadIdx.x;
    int wid = tid >> 6, lane = tid & 63;

    if (b & 1) {
        // ---- pre role: rows (b>>1)*4 + wid ----
        int i = (b >> 1) * 4 + wid;
        const float4* row = (const float4*)&adj[(size_t)i * NN];
        float4 v[12];
        #pragma unroll
        for (int c = 0; c < 12; ++c) v[c] = row[c * 64 + lane];   // all 12 loads in flight
        unsigned long long lmask = (1ull << lane) - 1ull;
        int base = 0;
        #pragma unroll
        for (int c = 0; c < 12; ++c) {
            #pragma unroll
            for (int k = 0; k < 4; ++k) {
                float vk = k == 0 ? v[c].x : k == 1 ? v[c].y : k == 2 ? v[c].z : v[c].w;
                bool nz = vk > 0.f;
                unsigned long long m = __ballot(nz);
                if (nz) {
                    int pos = base + __popcll(m & lmask);
                    if (pos < CAP) nbr[i * CAP + pos] = c * 256 + lane * 4 + k;
                }
                base += __popcll(m);
            }
        }
        if (lane == 0) cnt[i] = base < CAP ? base : CAP;
    } else {
        // ---- wh role: rows n0..n0+3, K split over 4 waves ----
        int n0 = (b >> 1) * 4;
        for (int idx = tid; idx < 512; idx += 256) {          // stage 4 rows of x as float4
            int r = idx >> 7, fq = idx & 127;
            *(float4*)&xs[r][fq * 4] = ((const float4*)x)[(size_t)(n0 + r) * (FEAT / 4) + fq];
        }
        __syncthreads();
        const float* wp = W + (lane >> 3) * (FEAT * 8) + (lane & 7);  // column base for this lane
        int f0 = wid * (FEAT / 4);
        float acc0 = 0.f, acc1 = 0.f, acc2 = 0.f, acc3 = 0.f;
        #pragma unroll 8
        for (int f = f0; f < f0 + FEAT / 4; ++f) {
            float wt = wp[f * 8];
            acc0 = fmaf(xs[0][f], wt, acc0);
            acc1 = fmaf(xs[1][f], wt, acc1);
            acc2 = fmaf(xs[2][f], wt, acc2);
            acc3 = fmaf(xs[3][f], wt, acc3);
        }
        part[wid][0][lane] = acc0;
        part[wid][1][lane] = acc1;
        part[wid][2][lane] = acc2;
        part[wid][3][lane] = acc3;
        __syncthreads();
        int n = n0 + wid;                                     // wave w finalizes row n0+w
        float v = part[0][wid][lane] + part[1][wid][lane] + part[2][wid][lane] + part[3][wid][lane];
        Wh[n * HD + lane] = v;
        float t1 = v * a1[lane];
        float t2 = v * a2[lane];
        for (int m = 1; m < 8; m <<= 1) {
            t1 += __shfl_xor(t1, m, 64);
            t2 += __shfl_xor(t2, m, 64);
        }
        if ((lane & 7) == 0) {
            int h = lane >> 3;
            s1t[n * 8 + h] = t1;
            s2t[n * 8 + h] = t2;
        }
    }
}

// K2: attention + ELU + fused P/Q. 8 waves = 8 rows per block; W1 staged in LDS.
__global__ __launch_bounds__(512) void k_attn_pq(const float* __restrict__ Wh, const float* __restrict__ s1t,
                                                 const float* __restrict__ s2t, const int* __restrict__ nbr,
                                                 const int* __restrict__ cnt, const float* __restrict__ W1,
                                                 const float* __restrict__ b1, float* __restrict__ P,
                                                 float* __restrict__ Q) {
    __shared__ float W1s[2 * HD][HD];          // 32 KB
    __shared__ int   jbuf[AROWS][CAP];         //  3 KB
    __shared__ float ebuf[AROWS][8][CAPP];     // 24.8 KB
    __shared__ float es[AROWS][HD];            //  2 KB
    int tid = threadIdx.x;
    int wid = tid >> 6;
    int lane = tid & 63;                       // lane = h*8+d
    int i = blockIdx.x * AROWS + wid;
    int h = lane >> 3, d = lane & 7;
    int ni = cnt[i];                           // issue early
    float s1i = s1t[i * 8 + h];
    for (int k = lane; k < CAP; k += 64)       // gather neighbor list (latency overlaps staging)
        if (k < ni) jbuf[wid][k] = nbr[i * CAP + k];
    for (int idx = tid; idx < 2048; idx += 512)   // stage W1: 2048 float4
        ((float4*)W1s)[idx] = ((const float4*)W1)[idx];
    __syncthreads();
    float mloc = -INFINITY;
    for (int k = d; k < ni; k += 8) {          // logits in parallel across d-lanes
        int j = jbuf[wid][k];
        float ev = s1i + s2t[j * 8 + h];
        ev = ev > 0.f ? ev : ALPHA * ev;
        ebuf[wid][h][k] = ev;
        mloc = fmaxf(mloc, ev);
    }
    mloc = fmaxf(mloc, __shfl_xor(mloc, 1, 8));
    mloc = fmaxf(mloc, __shfl_xor(mloc, 2, 8));
    mloc = fmaxf(mloc, __shfl_xor(mloc, 4, 8));
    __syncthreads();
    float denom = 0.f, acc = 0.f;
    for (int k = 0; k < ni; ++k) {
        float p = __expf(ebuf[wid][h][k] - mloc);
        denom += p;
        acc = fmaf(p, Wh[jbuf[wid][k] * HD + lane], acc);
    }
    float o = acc / denom;
    o = o > 0.f ? o : expm1f(o);               // ELU
    es[wid][lane] = o;
    __syncthreads();
    float p = b1[lane], q = 0.f;
    #pragma unroll 8
    for (int k = 0; k < HD; ++k) {
        float e = es[wid][k];                  // broadcast, conflict-free
        p = fmaf(e, W1s[k][lane], p);
        q = fmaf(e, W1s[HD + k][lane], q);
    }
    P[i * HD + lane] = p;
    Q[i * HD + lane] = q;
}

// K3: 16 lanes per edge; each group owns e, e+32768, e+65536 (+tail) processed
//     CONCURRENTLY (6 gathers in flight, interleaved butterflies), branchless lse.
__global__ __launch_bounds__(256) void k_cls(const float* __restrict__ P, const float* __restrict__ Q,
                                             const int* __restrict__ L, const int* __restrict__ R,
                                             const int* __restrict__ label, const float* __restrict__ W2,
                                             const float* __restrict__ b2, float* __restrict__ partials) {
    int tid = threadIdx.x;
    int sl = tid & 15;
    int g = (blockIdx.x * 256 + tid) >> 4;     // 0..32767
    float2 wa = *(const float2*)&W2[(sl * 4 + 0) * 2];
    float2 wb = *(const float2*)&W2[(sl * 4 + 1) * 2];
    float2 wc = *(const float2*)&W2[(sl * 4 + 2) * 2];
    float2 wd = *(const float2*)&W2[(sl * 4 + 3) * 2];
    float b20 = b2[0], b21 = b2[1];

    int e0 = g, e1 = g + 32768, e2 = g + 65536;          // all < 100000
    int ln0 = L[e0], rn0 = R[e0], lb0 = label[e0];
    int ln1 = L[e1], rn1 = R[e1], lb1 = label[e1];
    int ln2 = L[e2], rn2 = R[e2], lb2 = label[e2];
    float4 p0 = *(const float4*)&P[ln0 * HD + sl * 4];
    float4 q0 = *(const float4*)&Q[rn0 * HD + sl * 4];
    float4 p1 = *(const float4*)&P[ln1 * HD + sl * 4];
    float4 q1 = *(const float4*)&Q[rn1 * HD + sl * 4];
    float4 p2 = *(const float4*)&P[ln2 * HD + sl * 4];
    float4 q2 = *(const float4*)&Q[rn2 * HD + sl * 4];

    float v00 = fmaxf(p0.x + q0.x, 0.f), v01 = fmaxf(p0.y + q0.y, 0.f);
    float v02 = fmaxf(p0.z + q0.z, 0.f), v03 = fmaxf(p0.w + q0.w, 0.f);
    float v10 = fmaxf(p1.x + q1.x, 0.f), v11 = fmaxf(p1.y + q1.y, 0.f);
    float v12 = fmaxf(p1.z + q1.z, 0.f), v13 = fmaxf(p1.w + q1.w, 0.f);
    float v20 = fmaxf(p2.x + q2.x, 0.f), v21 = fmaxf(p2.y + q2.y, 0.f);
    float v22 = fmaxf(p2.z + q2.z, 0.f), v23 = fmaxf(p2.w + q2.w, 0.f);

    float t00 = v00 * wa.x + v01 * wb.x + v02 * wc.x + v03 * wd.x;
    float t01 = v00 * wa.y + v01 * wb.y + v02 * wc.y + v03 * wd.y;
    float t10 = v10 * wa.x + v11 * wb.x + v12 * wc.x + v13 * wd.x;
    float t11 = v10 * wa.y + v11 * wb.y + v12 * wc.y + v13 * wd.y;
    float t20 = v20 * wa.x + v21 * wb.x + v22 * wc.x + v23 * wd.x;
    float t21 = v20 * wa.y + v21 * wb.y + v22 * wc.y + v23 * wd.y;
    #pragma unroll
    for (int m = 1; m < 16; m <<= 1) {                   // 3 edges interleaved
        t00 += __shfl_xor(t00, m, 64);  t01 += __shfl_xor(t01, m, 64);
        t10 += __shfl_xor(t10, m, 64);  t11 += __shfl_xor(t11, m, 64);
        t20 += __shfl_xor(t20, m, 64);  t21 += __shfl_xor(t21, m, 64);
    }
    float sum;
    {
        float l0 = t00 + b20, l1 = t01 + b21;
        float mx = fmaxf(l0, l1);
        sum = mx + __logf(__expf(l0 - mx) + __expf(l1 - mx)) - (lb0 ? l1 : l0);
        l0 = t10 + b20; l1 = t11 + b21; mx = fmaxf(l0, l1);
        sum += mx + __logf(__expf(l0 - mx) + __expf(l1 - mx)) - (lb1 ? l1 : l0);
        l0 = t20 + b20; l1 = t21 + b21; mx = fmaxf(l0, l1);
        sum += mx + __logf(__expf(l0 - mx) + __expf(l1 - mx)) - (lb2 ? l1 : l0);
    }
    if (g + 98304 < NE) {                                // tail edge; wave-uniform (1696%4==0)
        int e3 = g + 98304;
        int ln3 = L[e3], rn3 = R[e3], lb3 = label[e3];
        float4 p3 = *(const float4*)&P[ln3 * HD + sl * 4];
        float4 q3 = *(const float4*)&Q[rn3 * HD + sl * 4];
        float w0 = fmaxf(p3.x + q3.x, 0.f), w1 = fmaxf(p3.y + q3.y, 0.f);
        float w2 = fmaxf(p3.z + q3.z, 0.f), w3 = fmaxf(p3.w + q3.w, 0.f);
        float t30 = w0 * wa.x + w1 * wb.x + w2 * wc.x + w3 * wd.x;
        float t31 = w0 * wa.y + w1 * wb.y + w2 * wc.y + w3 * wd.y;
        #pragma unroll
        for (int m = 1; m < 16; m <<= 1) {
            t30 += __shfl_xor(t30, m, 64);  t31 += __shfl_xor(t31, m, 64);
        }
        float l0 = t30 + b20, l1 = t31 + b21;
        float mx = fmaxf(l0, l1);
        sum += mx + __logf(__expf(l0 - mx) + __expf(l1 - mx)) - (lb3 ? l1 : l0);
    }
    sum = (sl == 0) ? sum : 0.f;                         // one contribution per group
    #pragma unroll
    for (int m = 1; m < 64; m <<= 1) sum += __shfl_xor(sum, m, 64);   // wave total
    __shared__ float wsum[4];
    if ((tid & 63) == 0) wsum[tid >> 6] = sum;
    __syncthreads();
    if (tid == 0) partials[blockIdx.x] = wsum[0] + wsum[1] + wsum[2] + wsum[3];
}

// K4: reduce 2048 partials -> mean
__global__ __launch_bounds__(1024) void k_reduce(const float* __restrict__ partials, float* __restrict__ out) {
    __shared__ float sh[1024];
    int t = threadIdx.x;
    sh[t] = partials[t] + partials[t + 1024];
    __syncthreads();
    for (int s = 512; s > 0; s >>= 1) {
        if (t < s) sh[t] += sh[t + s];
        __syncthreads();
    }
    if (t == 0) out[0] = sh[0] / (float)NE;
}

extern "C" void kernel_launch(void* const* d_in, const int* in_sizes, int n_in,
                              void* d_out, int out_size, void* d_ws, size_t ws_size,
                              hipStream_t stream) {
    const float* x     = (const float*)d_in[0];
    const float* adj   = (const float*)d_in[1];
    const int*   L     = (const int*)d_in[2];
    const int*   R     = (const int*)d_in[3];
    const int*   label = (const int*)d_in[4];
    const float* W     = (const float*)d_in[5];
    const float* a1    = (const float*)d_in[6];
    const float* a2    = (const float*)d_in[7];
    const float* W1    = (const float*)d_in[8];
    const float* b1    = (const float*)d_in[9];
    const float* W2    = (const float*)d_in[10];
    const float* b2    = (const float*)d_in[11];

    char* ws = (char*)d_ws;
    float* Wh       = (float*)(ws + 0);         //  786432 B
    float* s1t      = (float*)(ws + 786432);    //   98304 B   [N][8]
    float* s2t      = (float*)(ws + 884736);    //   98304 B   [N][8]
    int*   cnt      = (int*)  (ws + 983040);    //   12288 B
    int*   nbr      = (int*)  (ws + 995328);    // 1179648 B
    float* P        = (float*)(ws + 2174976);   //  786432 B
    float* Q        = (float*)(ws + 2961408);   //  786432 B
    float* partials = (float*)(ws + 3747840);   //    8192 B

    k_stage1<<<2 * (NN / 4), 256, 0, stream>>>(adj, x, W, a1, a2, nbr, cnt, Wh, s1t, s2t);
    k_attn_pq<<<NN / AROWS, 512, 0, stream>>>(Wh, s1t, s2t, nbr, cnt, W1, b1, P, Q);
    k_cls<<<K5_BLOCKS, 256, 0, stream>>>(P, Q, L, R, label, W2, b2, partials);
    k_reduce<<<1, 1024, 0, stream>>>(partials, (float*)d_out);
}